// Round 11
// baseline (285.704 us; speedup 1.0000x reference)
//
#include <hip/hip_runtime.h>

// Problem constants (fixed by setup_inputs) — float inputs are FP32.
#define NB 8
#define NN 4096
#define DEG 16
#define UN 128
#define NE (NN*DEG)
#define SC 1.2304489f   // fp32(log(17)/log(10))

typedef unsigned short u16;
typedef __attribute__((ext_vector_type(8))) short short8;  // 8 bf16 = 4 VGPRs
typedef __attribute__((ext_vector_type(4))) float f32x4;

__device__ __forceinline__ float b2f(u16 v) { return __uint_as_float(((unsigned)v) << 16); }
// round-to-nearest-even fp32 -> bf16
__device__ __forceinline__ u16 f2b(float f) {
    unsigned u = __float_as_uint(f);
    unsigned r = ((u >> 16) & 1u) + 0x7FFFu;
    return (u16)((u + r) >> 16);
}

// ---------------------------------------------------------------------------
// Prep: fold W -> transposed bf16 B-mats + BN consts; zero batch counters.
//   AsumT[d][u][j] = ((W0+s(W1+W2))/16 + W6+s(W7+W8))^T, AmaxT = (W3+s(W4+W5))^T
//   k = gamma*rsqrt(var+eps), c = beta - mean*k
// grid 384, block 128.
// ---------------------------------------------------------------------------
__global__ void pna11_prep(const float* W, const float* bias, const float* gamma,
                           const float* beta, const float* mmean, const float* mvar,
                           u16* AsumT, u16* AmaxT, float* biasf, float* kv, float* cv,
                           int* counters) {
    const int bid = blockIdx.x;
    const int t = threadIdx.x;  // 128
    if (bid == 0 && t < 16) counters[t] = 0;
    const int d = bid >> 7;        // 0..2
    const int j = bid & 127;
    const int u = t;
    const float* Wd = W + (size_t)d * 9 * UN * UN;
    float w[9];
#pragma unroll
    for (int r = 0; r < 9; r++) w[r] = Wd[(size_t)(r * UN + j) * UN + u];
    float asum = (w[0] + SC * (w[1] + w[2])) * 0.0625f + w[6] + SC * (w[7] + w[8]);
    float amax = w[3] + SC * (w[4] + w[5]);
    AsumT[((size_t)d * UN + u) * UN + j] = f2b(asum);
    AmaxT[((size_t)d * UN + u) * UN + j] = f2b(amax);
    if (j == 0) {
        float k = gamma[d * UN + u] * rsqrtf(mvar[d * UN + u] + 1e-3f);
        kv[d * UN + u] = k;
        cv[d * UN + u] = beta[d * UN + u] - mmean[d * UN + u] * k;
        biasf[d * UN + u] = bias[d * UN + u];
    }
}

// ---------------------------------------------------------------------------
// PNA layer, occupancy-first. grid 2048 (b = bid&7 XCD-pin, 16-node tile),
// block 256 (4 waves), __launch_bounds__(256,8) -> target 8 blocks/CU.
// MODE 0: fp32 x in -> bf16 x out  (layer 0)
// MODE 1: bf16 x in -> bf16 x out  (layer 1)
// MODE 2: bf16 x in -> fused per-tile node-sum; last block per batch runs MLP.
// Phase 1: gather-aggregate -> s_sum/s_max bf16 LDS [16][136].
// Phase 2: wave w computes C[16, units w*32..+31] = sS@Asum + sM@Amax via
//          mfma_f32_16x16x32_bf16 (K=128 per mat), B-frags from global (L2-hot).
// ---------------------------------------------------------------------------
template <int MODE>
__global__ __launch_bounds__(256, 8) void pna11_layer(
        const void* __restrict__ xin_v, const int* __restrict__ eidx,
        const u16* __restrict__ AsumT, const u16* __restrict__ AmaxT,
        const float* __restrict__ biasf, const float* __restrict__ kv,
        const float* __restrict__ cv,
        u16* __restrict__ xout, float* __restrict__ partial,
        int* __restrict__ counters,
        const float* __restrict__ Wp1, const float* __restrict__ bp1,
        const float* __restrict__ Wp2, const float* __restrict__ bp2,
        float* __restrict__ out, int d) {
    const int bid = blockIdx.x;
    const int b = bid & 7;               // batch -> XCD pin
    const int tile = bid >> 3;           // 0..255
    const int node0 = tile * 16;
    const int t = threadIdx.x;           // 256
    const int w = t >> 6, lane = t & 63;
    const int l15 = lane & 15, quad = lane >> 4;

    __shared__ u16 sS[16][136];          // s_sum bf16 (row stride 272 B)
    __shared__ u16 sM[16][136];          // s_max bf16
    __shared__ int sidx[16 * DEG];       // 256 == blockDim
    __shared__ float gmean_s[UN];
    __shared__ float mlp1[UN];
    __shared__ int is_last;

    sidx[t] = eidx[((size_t)b * NE + (size_t)node0 * DEG + t) * 2 + 1] & (NN - 1);
    __syncthreads();

    if (MODE == 0) {
        // fp32 gather: 32-lane group per node (float4 = 4 feats/lane), 2 iters
        const int sub = (t >> 5) & 1;    // group within wave
        const int ln = t & 31;
        const float* xb = (const float*)xin_v + (size_t)b * NN * UN;
#pragma unroll
        for (int it = 0; it < 2; it++) {
            const int nl = it * 8 + w * 2 + sub;
            const int* ip = sidx + nl * DEG;
            float s0 = 0.f, s1 = 0.f, s2 = 0.f, s3 = 0.f;
            float m0 = -1e30f, m1 = -1e30f, m2 = -1e30f, m3 = -1e30f;
#pragma unroll
            for (int ep = 0; ep < 4; ep++) {
                float4 x0 = *(const float4*)(xb + (size_t)ip[ep * 4 + 0] * UN + ln * 4);
                float4 x1 = *(const float4*)(xb + (size_t)ip[ep * 4 + 1] * UN + ln * 4);
                float4 x2 = *(const float4*)(xb + (size_t)ip[ep * 4 + 2] * UN + ln * 4);
                float4 x3 = *(const float4*)(xb + (size_t)ip[ep * 4 + 3] * UN + ln * 4);
                s0 += x0.x + x1.x + x2.x + x3.x;
                s1 += x0.y + x1.y + x2.y + x3.y;
                s2 += x0.z + x1.z + x2.z + x3.z;
                s3 += x0.w + x1.w + x2.w + x3.w;
                m0 = fmaxf(fmaxf(m0, x0.x), fmaxf(fmaxf(x1.x, x2.x), x3.x));
                m1 = fmaxf(fmaxf(m1, x0.y), fmaxf(fmaxf(x1.y, x2.y), x3.y));
                m2 = fmaxf(fmaxf(m2, x0.z), fmaxf(fmaxf(x1.z, x2.z), x3.z));
                m3 = fmaxf(fmaxf(m3, x0.w), fmaxf(fmaxf(x1.w, x2.w), x3.w));
            }
            ushort4 os = { f2b(s0), f2b(s1), f2b(s2), f2b(s3) };
            ushort4 om = { f2b(m0), f2b(m1), f2b(m2), f2b(m3) };
            *(ushort4*)(&sS[nl][ln * 4]) = os;
            *(ushort4*)(&sM[nl][ln * 4]) = om;
        }
    } else {
        // bf16 gather: 16-lane group per node (uint4 = 8 feats/lane), 1 iter
        const int nl = w * 4 + quad;
        const int* ip = sidx + nl * DEG;
        const u16* xb = (const u16*)xin_v + (size_t)b * NN * UN;
        float s[8] = {0, 0, 0, 0, 0, 0, 0, 0};
        float m[8];
#pragma unroll
        for (int c = 0; c < 8; c++) m[c] = -1e30f;
#pragma unroll
        for (int ep = 0; ep < 4; ep++) {
            uint4 r0 = *(const uint4*)(xb + (size_t)ip[ep * 4 + 0] * UN + l15 * 8);
            uint4 r1 = *(const uint4*)(xb + (size_t)ip[ep * 4 + 1] * UN + l15 * 8);
            uint4 r2 = *(const uint4*)(xb + (size_t)ip[ep * 4 + 2] * UN + l15 * 8);
            uint4 r3 = *(const uint4*)(xb + (size_t)ip[ep * 4 + 3] * UN + l15 * 8);
            const unsigned* rr[4] = { &r0.x, &r1.x, &r2.x, &r3.x };
#pragma unroll
            for (int e = 0; e < 4; e++) {
#pragma unroll
                for (int h = 0; h < 4; h++) {
                    unsigned v = rr[e][h];
                    float lo = __uint_as_float(v << 16);
                    float hi = __uint_as_float(v & 0xffff0000u);
                    s[h * 2]     += lo;  m[h * 2]     = fmaxf(m[h * 2], lo);
                    s[h * 2 + 1] += hi;  m[h * 2 + 1] = fmaxf(m[h * 2 + 1], hi);
                }
            }
        }
        u16 os[8], om[8];
#pragma unroll
        for (int c = 0; c < 8; c++) { os[c] = f2b(s[c]); om[c] = f2b(m[c]); }
        *(uint4*)(&sS[nl][l15 * 8]) = *(const uint4*)os;
        *(uint4*)(&sM[nl][l15 * 8]) = *(const uint4*)om;
    }
    __syncthreads();

    // MFMA: wave w -> units [w*32, w*32+32), all 16 m-rows
    const u16* Bs = AsumT + (size_t)d * UN * UN;
    const u16* Bm = AmaxT + (size_t)d * UN * UN;
    f32x4 acc[2] = {};
#pragma unroll
    for (int k0 = 0; k0 < 4; k0++) {
        short8 aS = *(const short8*)(&sS[l15][k0 * 32 + quad * 8]);
        short8 aM = *(const short8*)(&sM[l15][k0 * 32 + quad * 8]);
#pragma unroll
        for (int nt = 0; nt < 2; nt++) {
            const int ng = w * 2 + nt;
            short8 bS = *(const short8*)(Bs + (size_t)(ng * 16 + l15) * UN + k0 * 32 + quad * 8);
            short8 bM = *(const short8*)(Bm + (size_t)(ng * 16 + l15) * UN + k0 * 32 + quad * 8);
            acc[nt] = __builtin_amdgcn_mfma_f32_16x16x32_bf16(aS, bS, acc[nt], 0, 0, 0);
            acc[nt] = __builtin_amdgcn_mfma_f32_16x16x32_bf16(aM, bM, acc[nt], 0, 0, 0);
        }
    }

    if (MODE < 2) {
        // epilogue: y = relu(acc+bias)*k + c -> bf16, staged via LDS.
        // C-map: node = quad*4 + r, unit = ng*16 + l15.
        __syncthreads();
#pragma unroll
        for (int nt = 0; nt < 2; nt++) {
            const int u = (w * 2 + nt) * 16 + l15;
            const float bb = biasf[d * UN + u], kk = kv[d * UN + u], cc = cv[d * UN + u];
#pragma unroll
            for (int r = 0; r < 4; r++) {
                float y = fmaxf(acc[nt][r] + bb, 0.0f) * kk + cc;
                sS[quad * 4 + r][u] = f2b(y);
            }
        }
        __syncthreads();
        {
            int r = t >> 4, c0 = (t & 15) * 8;
            *(uint4*)(xout + ((size_t)b * NN + node0 + r) * UN + c0) =
                *(const uint4*)(&sS[r][c0]);
        }
    } else {
        // fused readout stage 1: per-unit sum over this tile's 16 nodes
        float* red = (float*)sM;   // [4 quads][128 units]
        __syncthreads();
#pragma unroll
        for (int nt = 0; nt < 2; nt++) {
            const int u = (w * 2 + nt) * 16 + l15;
            const float bb = biasf[d * UN + u], kk = kv[d * UN + u], cc = cv[d * UN + u];
            float s = 0.0f;
#pragma unroll
            for (int r = 0; r < 4; r++)
                s += fmaxf(acc[nt][r] + bb, 0.0f) * kk + cc;
            red[quad * UN + u] = s;
        }
        __syncthreads();
        if (t < UN) {
            float s = red[t] + red[UN + t] + red[2 * UN + t] + red[3 * UN + t];
            partial[((size_t)b * 256 + tile) * UN + t] = s;
        }
        __syncthreads();
        if (t == 0) {
            __threadfence();                       // release partial stores
            int old = atomicAdd(&counters[b], 1);  // device-scope
            is_last = (old == 255);
        }
        __syncthreads();
        if (is_last) {
            __threadfence();                       // acquire other tiles' partials
            if (t < UN) {
                float s = 0.0f;
                for (int c = 0; c < 256; c++)
                    s += partial[((size_t)b * 256 + c) * UN + t];
                gmean_s[t] = s * (1.0f / (float)NN);
            }
            __syncthreads();
            if (t < UN) {
                float a = bp1[t];
                for (int j = 0; j < UN; j++)
                    a += gmean_s[j] * Wp1[j * UN + t];
                mlp1[t] = fmaxf(a, 0.0f);
            }
            __syncthreads();
            if (t < 64) {
                float o = bp2[t];
                for (int j = 0; j < UN; j++)
                    o += mlp1[j] * Wp2[j * 64 + t];
                out[b * 64 + t] = fmaxf(o, 0.0f);
            }
        }
    }
}

extern "C" void kernel_launch(void* const* d_in, const int* in_sizes, int n_in,
                              void* d_out, int out_size, void* d_ws, size_t ws_size,
                              hipStream_t stream) {
    const float* xattr = (const float*)d_in[0];   // [8,4096,128] fp32
    const int*   eidx  = (const int*)d_in[1];     // [8,65536,2] int32
    const float* W     = (const float*)d_in[2];   // [3,1152,128] fp32
    const float* bias  = (const float*)d_in[3];
    const float* gamma = (const float*)d_in[4];
    const float* beta  = (const float*)d_in[5];
    const float* mmean = (const float*)d_in[6];
    const float* mvar  = (const float*)d_in[7];
    const float* Wp1   = (const float*)d_in[8];   // [128,128]
    const float* bp1   = (const float*)d_in[9];
    const float* Wp2   = (const float*)d_in[10];  // [128,64]
    const float* bp2   = (const float*)d_in[11];
    float* out = (float*)d_out;                   // [8,64] fp32

    u16* AsumT = (u16*)d_ws;                        // 3*128*128 bf16
    u16* AmaxT = AsumT + 3 * UN * UN;               // 3*128*128 bf16
    float* biasf = (float*)(AmaxT + 3 * UN * UN);   // 3*128 fp32
    float* kv = biasf + 3 * UN;
    float* cv = kv + 3 * UN;
    int* counters = (int*)(cv + 3 * UN);            // 16 ints
    float* partial = (float*)(counters + 16);       // [8,256,128] fp32
    u16* buf0 = (u16*)(partial + (size_t)NB * 256 * UN);  // [8,4096,128] bf16
    u16* buf1 = buf0 + (size_t)NB * NN * UN;

    pna11_prep<<<384, 128, 0, stream>>>(W, bias, gamma, beta, mmean, mvar,
                                        AsumT, AmaxT, biasf, kv, cv, counters);
    pna11_layer<0><<<2048, 256, 0, stream>>>(xattr, eidx, AsumT, AmaxT, biasf, kv, cv,
                                             buf0, partial, counters,
                                             Wp1, bp1, Wp2, bp2, out, 0);
    pna11_layer<1><<<2048, 256, 0, stream>>>(buf0, eidx, AsumT, AmaxT, biasf, kv, cv,
                                             buf1, partial, counters,
                                             Wp1, bp1, Wp2, bp2, out, 1);
    pna11_layer<2><<<2048, 256, 0, stream>>>(buf1, eidx, AsumT, AmaxT, biasf, kv, cv,
                                             (u16*)nullptr, partial, counters,
                                             Wp1, bp1, Wp2, bp2, out, 2);
}

// Round 12
// 163.105 us; speedup vs baseline: 1.7517x; 1.7517x over previous
//
#include <hip/hip_runtime.h>

// Problem constants (fixed by setup_inputs) — float inputs are FP32.
#define NB 8
#define NN 4096
#define DEG 16
#define UN 128
#define NE (NN*DEG)
#define SC 1.2304489f   // fp32(log(17)/log(10))

typedef unsigned short u16;
typedef __attribute__((ext_vector_type(8))) short short8;  // 8 bf16 = 4 VGPRs
typedef __attribute__((ext_vector_type(4))) float f32x4;

__device__ __forceinline__ float b2f(u16 v) { return __uint_as_float(((unsigned)v) << 16); }
// round-to-nearest-even fp32 -> bf16
__device__ __forceinline__ u16 f2b(float f) {
    unsigned u = __float_as_uint(f);
    unsigned r = ((u >> 16) & 1u) + 0x7FFFu;
    return (u16)((u + r) >> 16);
}

// ---------------------------------------------------------------------------
// Prep: fold W -> transposed bf16 B-mats + BN consts; zero batch counters.
//   AsumT[d][u][j] = ((W0+s(W1+W2))/16 + W6+s(W7+W8))^T, AmaxT = (W3+s(W4+W5))^T
//   k = gamma*rsqrt(var+eps), c = beta - mean*k
// grid 384, block 128.
// ---------------------------------------------------------------------------
__global__ void pna12_prep(const float* W, const float* bias, const float* gamma,
                           const float* beta, const float* mmean, const float* mvar,
                           u16* AsumT, u16* AmaxT, float* biasf, float* kv, float* cv,
                           int* counters) {
    const int bid = blockIdx.x;
    const int t = threadIdx.x;  // 128
    if (bid == 0 && t < 16) counters[t] = 0;
    const int d = bid >> 7;
    const int j = bid & 127;
    const int u = t;
    const float* Wd = W + (size_t)d * 9 * UN * UN;
    float w[9];
#pragma unroll
    for (int r = 0; r < 9; r++) w[r] = Wd[(size_t)(r * UN + j) * UN + u];
    float asum = (w[0] + SC * (w[1] + w[2])) * 0.0625f + w[6] + SC * (w[7] + w[8]);
    float amax = w[3] + SC * (w[4] + w[5]);
    AsumT[((size_t)d * UN + u) * UN + j] = f2b(asum);
    AmaxT[((size_t)d * UN + u) * UN + j] = f2b(amax);
    if (j == 0) {
        float k = gamma[d * UN + u] * rsqrtf(mvar[d * UN + u] + 1e-3f);
        kv[d * UN + u] = k;
        cv[d * UN + u] = beta[d * UN + u] - mmean[d * UN + u] * k;
        biasf[d * UN + u] = bias[d * UN + u];
    }
}

// ---------------------------------------------------------------------------
// PNA layer. grid 1024 (b = bid&7 XCD-pin, 32-node tile = bid>>3), block 256,
// __launch_bounds__(256,4): exactly 4 blocks/CU -> FULL grid co-residency at
// dispatch => bid&7 pinning holds (lesson from r11: partial residency breaks
// pinning and thrashes L2).
// MODE 0: fp32 x in -> bf16 x out; MODE 1: bf16 -> bf16;
// MODE 2: bf16 in -> fused per-tile node-sum; last block per batch runs MLP.
// Phase 2: wave w -> units [w*32,+32), m-subtiles {0,1} of 16 nodes;
//          mfma_f32_16x16x32_bf16, B-frags from global (L1/L2-hot).
// ---------------------------------------------------------------------------
template <int MODE>
__global__ __launch_bounds__(256, 4) void pna12_layer(
        const void* __restrict__ xin_v, const int* __restrict__ eidx,
        const u16* __restrict__ AsumT, const u16* __restrict__ AmaxT,
        const float* __restrict__ biasf, const float* __restrict__ kv,
        const float* __restrict__ cv,
        u16* __restrict__ xout, float* __restrict__ partial,
        int* __restrict__ counters,
        const float* __restrict__ Wp1, const float* __restrict__ bp1,
        const float* __restrict__ Wp2, const float* __restrict__ bp2,
        float* __restrict__ out, int d) {
    const int bid = blockIdx.x;
    const int b = bid & 7;               // batch -> XCD pin
    const int tile = bid >> 3;           // 0..127
    const int node0 = tile * 32;
    const int t = threadIdx.x;           // 256
    const int w = t >> 6, lane = t & 63;
    const int l15 = lane & 15, quad = lane >> 4;

    __shared__ u16 sS[32][136];          // s_sum bf16 (row stride 272 B)
    __shared__ u16 sM[32][136];          // s_max bf16
    __shared__ int sidx[32 * DEG];       // 512 edges
    __shared__ float gmean_s[UN];
    __shared__ float mlp1[UN];
    __shared__ int is_last;

#pragma unroll
    for (int k = 0; k < 2; k++)
        sidx[t * 2 + k] = eidx[((size_t)b * NE + (size_t)node0 * DEG + t * 2 + k) * 2 + 1] & (NN - 1);
    __syncthreads();

    if (MODE == 0) {
        // fp32 gather: 32-lane group per node (float4), 8 nodes/wave over 4 iters
        const int sub = (lane >> 5) & 1;
        const int ln = lane & 31;
        const float* xb = (const float*)xin_v + (size_t)b * NN * UN;
#pragma unroll
        for (int it = 0; it < 4; it++) {
            const int nl = w * 8 + it * 2 + sub;
            const int* ip = sidx + nl * DEG;
            float s0 = 0.f, s1 = 0.f, s2 = 0.f, s3 = 0.f;
            float m0 = -1e30f, m1 = -1e30f, m2 = -1e30f, m3 = -1e30f;
#pragma unroll
            for (int ep = 0; ep < 4; ep++) {
                float4 x0 = *(const float4*)(xb + (size_t)ip[ep * 4 + 0] * UN + ln * 4);
                float4 x1 = *(const float4*)(xb + (size_t)ip[ep * 4 + 1] * UN + ln * 4);
                float4 x2 = *(const float4*)(xb + (size_t)ip[ep * 4 + 2] * UN + ln * 4);
                float4 x3 = *(const float4*)(xb + (size_t)ip[ep * 4 + 3] * UN + ln * 4);
                s0 += x0.x + x1.x + x2.x + x3.x;
                s1 += x0.y + x1.y + x2.y + x3.y;
                s2 += x0.z + x1.z + x2.z + x3.z;
                s3 += x0.w + x1.w + x2.w + x3.w;
                m0 = fmaxf(fmaxf(m0, x0.x), fmaxf(fmaxf(x1.x, x2.x), x3.x));
                m1 = fmaxf(fmaxf(m1, x0.y), fmaxf(fmaxf(x1.y, x2.y), x3.y));
                m2 = fmaxf(fmaxf(m2, x0.z), fmaxf(fmaxf(x1.z, x2.z), x3.z));
                m3 = fmaxf(fmaxf(m3, x0.w), fmaxf(fmaxf(x1.w, x2.w), x3.w));
            }
            ushort4 os = { f2b(s0), f2b(s1), f2b(s2), f2b(s3) };
            ushort4 om = { f2b(m0), f2b(m1), f2b(m2), f2b(m3) };
            *(ushort4*)(&sS[nl][ln * 4]) = os;
            *(ushort4*)(&sM[nl][ln * 4]) = om;
        }
    } else {
        // bf16 gather: 16-lane group per node (uint4 = 8 feats), 8 nodes/wave
        const u16* xb = (const u16*)xin_v + (size_t)b * NN * UN;
#pragma unroll
        for (int it = 0; it < 2; it++) {
            const int nl = w * 8 + it * 4 + quad;
            const int* ip = sidx + nl * DEG;
            float s[8] = {0, 0, 0, 0, 0, 0, 0, 0};
            float m[8];
#pragma unroll
            for (int c = 0; c < 8; c++) m[c] = -1e30f;
#pragma unroll
            for (int ep = 0; ep < 4; ep++) {
                uint4 r0 = *(const uint4*)(xb + (size_t)ip[ep * 4 + 0] * UN + l15 * 8);
                uint4 r1 = *(const uint4*)(xb + (size_t)ip[ep * 4 + 1] * UN + l15 * 8);
                uint4 r2 = *(const uint4*)(xb + (size_t)ip[ep * 4 + 2] * UN + l15 * 8);
                uint4 r3 = *(const uint4*)(xb + (size_t)ip[ep * 4 + 3] * UN + l15 * 8);
                const unsigned* rr[4] = { &r0.x, &r1.x, &r2.x, &r3.x };
#pragma unroll
                for (int e = 0; e < 4; e++) {
#pragma unroll
                    for (int h = 0; h < 4; h++) {
                        unsigned v = rr[e][h];
                        float lo = __uint_as_float(v << 16);
                        float hi = __uint_as_float(v & 0xffff0000u);
                        s[h * 2]     += lo;  m[h * 2]     = fmaxf(m[h * 2], lo);
                        s[h * 2 + 1] += hi;  m[h * 2 + 1] = fmaxf(m[h * 2 + 1], hi);
                    }
                }
            }
            u16 os[8], om[8];
#pragma unroll
            for (int c = 0; c < 8; c++) { os[c] = f2b(s[c]); om[c] = f2b(m[c]); }
            *(uint4*)(&sS[nl][l15 * 8]) = *(const uint4*)os;
            *(uint4*)(&sM[nl][l15 * 8]) = *(const uint4*)om;
        }
    }
    __syncthreads();

    // MFMA: wave w -> units [w*32,+32) (ng = 2w,2w+1), m-subtiles 0,1
    const u16* Bs = AsumT + (size_t)d * UN * UN;
    const u16* Bm = AmaxT + (size_t)d * UN * UN;
    f32x4 acc[2][2] = {};
#pragma unroll
    for (int msub = 0; msub < 2; msub++) {
#pragma unroll
        for (int k0 = 0; k0 < 4; k0++) {
            short8 aS = *(const short8*)(&sS[msub * 16 + l15][k0 * 32 + quad * 8]);
            short8 aM = *(const short8*)(&sM[msub * 16 + l15][k0 * 32 + quad * 8]);
#pragma unroll
            for (int nt = 0; nt < 2; nt++) {
                const int ng = w * 2 + nt;
                short8 bS = *(const short8*)(Bs + (size_t)(ng * 16 + l15) * UN + k0 * 32 + quad * 8);
                short8 bM = *(const short8*)(Bm + (size_t)(ng * 16 + l15) * UN + k0 * 32 + quad * 8);
                acc[msub][nt] = __builtin_amdgcn_mfma_f32_16x16x32_bf16(aS, bS, acc[msub][nt], 0, 0, 0);
                acc[msub][nt] = __builtin_amdgcn_mfma_f32_16x16x32_bf16(aM, bM, acc[msub][nt], 0, 0, 0);
            }
        }
    }

    if (MODE < 2) {
        // epilogue: y = relu(acc+bias)*k + c -> bf16 via LDS staging.
        // C-map: node = msub*16 + quad*4 + r, unit = ng*16 + l15.
        __syncthreads();
#pragma unroll
        for (int nt = 0; nt < 2; nt++) {
            const int u = (w * 2 + nt) * 16 + l15;
            const float bb = biasf[d * UN + u], kk = kv[d * UN + u], cc = cv[d * UN + u];
#pragma unroll
            for (int msub = 0; msub < 2; msub++)
#pragma unroll
                for (int r = 0; r < 4; r++) {
                    float y = fmaxf(acc[msub][nt][r] + bb, 0.0f) * kk + cc;
                    sS[msub * 16 + quad * 4 + r][u] = f2b(y);
                }
        }
        __syncthreads();
#pragma unroll
        for (int p = 0; p < 2; p++) {
            int r = (t >> 4) + p * 16;
            int c0 = (t & 15) * 8;
            *(uint4*)(xout + ((size_t)b * NN + node0 + r) * UN + c0) =
                *(const uint4*)(&sS[r][c0]);
        }
    } else {
        // fused readout stage 1: per-unit sum over tile's 32 nodes
        float* red = (float*)sM;   // [4 quads][128 units] fp32
        __syncthreads();
#pragma unroll
        for (int nt = 0; nt < 2; nt++) {
            const int u = (w * 2 + nt) * 16 + l15;
            const float bb = biasf[d * UN + u], kk = kv[d * UN + u], cc = cv[d * UN + u];
            float s = 0.0f;
#pragma unroll
            for (int msub = 0; msub < 2; msub++)
#pragma unroll
                for (int r = 0; r < 4; r++)
                    s += fmaxf(acc[msub][nt][r] + bb, 0.0f) * kk + cc;
            red[quad * UN + u] = s;
        }
        __syncthreads();
        if (t < UN) {
            float s = red[t] + red[UN + t] + red[2 * UN + t] + red[3 * UN + t];
            partial[((size_t)b * 128 + tile) * UN + t] = s;
        }
        __syncthreads();
        if (t == 0) {
            __threadfence();                       // release partial stores
            int old = atomicAdd(&counters[b], 1);  // device-scope
            is_last = (old == 127);
        }
        __syncthreads();
        if (is_last) {
            __threadfence();                       // acquire other tiles' partials
            if (t < UN) {
                float s = 0.0f;
                for (int c = 0; c < 128; c++)
                    s += partial[((size_t)b * 128 + c) * UN + t];
                gmean_s[t] = s * (1.0f / (float)NN);
            }
            __syncthreads();
            if (t < UN) {
                float a = bp1[t];
                for (int j = 0; j < UN; j++)
                    a += gmean_s[j] * Wp1[j * UN + t];
                mlp1[t] = fmaxf(a, 0.0f);
            }
            __syncthreads();
            if (t < 64) {
                float o = bp2[t];
                for (int j = 0; j < UN; j++)
                    o += mlp1[j] * Wp2[j * 64 + t];
                out[b * 64 + t] = fmaxf(o, 0.0f);
            }
        }
    }
}

extern "C" void kernel_launch(void* const* d_in, const int* in_sizes, int n_in,
                              void* d_out, int out_size, void* d_ws, size_t ws_size,
                              hipStream_t stream) {
    const float* xattr = (const float*)d_in[0];   // [8,4096,128] fp32
    const int*   eidx  = (const int*)d_in[1];     // [8,65536,2] int32
    const float* W     = (const float*)d_in[2];   // [3,1152,128] fp32
    const float* bias  = (const float*)d_in[3];
    const float* gamma = (const float*)d_in[4];
    const float* beta  = (const float*)d_in[5];
    const float* mmean = (const float*)d_in[6];
    const float* mvar  = (const float*)d_in[7];
    const float* Wp1   = (const float*)d_in[8];   // [128,128]
    const float* bp1   = (const float*)d_in[9];
    const float* Wp2   = (const float*)d_in[10];  // [128,64]
    const float* bp2   = (const float*)d_in[11];
    float* out = (float*)d_out;                   // [8,64] fp32

    u16* AsumT = (u16*)d_ws;                        // 3*128*128 bf16
    u16* AmaxT = AsumT + 3 * UN * UN;               // 3*128*128 bf16
    float* biasf = (float*)(AmaxT + 3 * UN * UN);   // 3*128 fp32
    float* kv = biasf + 3 * UN;
    float* cv = kv + 3 * UN;
    int* counters = (int*)(cv + 3 * UN);            // 16 ints
    float* partial = (float*)(counters + 16);       // [8,128,128] fp32
    u16* buf0 = (u16*)(partial + (size_t)NB * 128 * UN);  // [8,4096,128] bf16
    u16* buf1 = buf0 + (size_t)NB * NN * UN;

    pna12_prep<<<384, 128, 0, stream>>>(W, bias, gamma, beta, mmean, mvar,
                                        AsumT, AmaxT, biasf, kv, cv, counters);
    pna12_layer<0><<<1024, 256, 0, stream>>>(xattr, eidx, AsumT, AmaxT, biasf, kv, cv,
                                             buf0, partial, counters,
                                             Wp1, bp1, Wp2, bp2, out, 0);
    pna12_layer<1><<<1024, 256, 0, stream>>>(buf0, eidx, AsumT, AmaxT, biasf, kv, cv,
                                             buf1, partial, counters,
                                             Wp1, bp1, Wp2, bp2, out, 1);
    pna12_layer<2><<<1024, 256, 0, stream>>>(buf1, eidx, AsumT, AmaxT, biasf, kv, cv,
                                             (u16*)nullptr, partial, counters,
                                             Wp1, bp1, Wp2, bp2, out, 2);
}